// Round 2
// baseline (1138.151 us; speedup 1.0000x reference)
//
#include <hip/hip_runtime.h>

// Problem dims (fixed by the reference setup)
#define Bn 8
#define Sn 2048
#define Dn 512
#define Gn 4
#define Cn 2048
#define DGn 128
#define Nn 16384  // B*S

// d_out layout (flat fp32, reference return order)
#define OFF_Q    0u        // quantize_st  [8,2048,512]  = 8388608
#define OFF_IND  8388608u  // ind_out      [8,2048,4]    = 65536 (float-encoded ints)
#define OFF_LOSS 8454144u  // commit_loss  scalar
#define OFF_CS   8454145u  // new_cluster_size [4,2048]  = 8192
#define OFF_AVG  8462337u  // new_embed_avg [4,2048,128] = 1048576
#define OFF_EMB  9510913u  // new_embed     [4,2048,128] = 1048576 (first 8192 temporarily hold ||E||^2)

__global__ void vq_init(const float* __restrict__ cs_in,
                        const float* __restrict__ avg_in,
                        float* __restrict__ out) {
    int i = blockIdx.x * 256 + threadIdx.x;
    if (i < Gn * Cn * DGn) out[OFF_AVG + i] = 0.8f * avg_in[i];
    if (i < Gn * Cn)       out[OFF_CS + i]  = 0.8f * cs_in[i];
    if (i == 0)            out[OFF_LOSS] = 0.0f;
}

// one wave per code row: ||E[g,c]||^2 -> stash at OFF_EMB (overwritten by finalize)
__global__ void vq_enorm(const float* __restrict__ embed,
                         float* __restrict__ out) {
    int gid  = blockIdx.x * 256 + threadIdx.x;
    int wave = gid >> 6;            // 0..8191
    int lane = gid & 63;
    const float* row = embed + (size_t)wave * DGn;
    float a = row[lane], b = row[lane + 64];
    float v = fmaf(a, a, b * b);
    #pragma unroll
    for (int off = 32; off; off >>= 1) v += __shfl_xor(v, off, 64);
    if (lane == 0) out[OFF_EMB + wave] = v;
}

// Main fused kernel: block = (g, 128-row tile) x 256-code tiles iterated.
// 256 threads, per-thread 8m x 16c accumulators. All LDS accesses <=2-way (free).
__launch_bounds__(256, 2)
__global__ void vq_main(const float* __restrict__ x,
                        const float* __restrict__ embed,
                        float* __restrict__ out) {
    __shared__ float As[DGn][128];   // A transposed [k][m], 64 KB. bank(k,m)=m%32 -> reads/writes 2-way
    __shared__ float Es[16][256];    // E k-slice [k][c], 16 KB.  bank(k,c)=c%32 -> 2-way

    const int t  = threadIdx.x;
    const int g  = blockIdx.x >> 7;
    const int n0 = (blockIdx.x & 127) * 128;
    const int tr = t & 15;           // m-lane: covers banks 4*tr in 0..60
    const int tc = t >> 4;           // c-lane: 0..15

    const float* xg = x + (size_t)n0 * Dn + g * DGn;
    const float* eg = embed + (size_t)g * Cn * DGn;
    const float* enorm_g = out + OFF_EMB + g * Cn;

    // ---- stage A transposed: lane-per-row mapping -> scalar writes are 2-way (free) ----
    {
        const int arow = t & 127, ah = t >> 7;
        const float* xrow = xg + (size_t)arow * Dn;
        #pragma unroll
        for (int j = 0; j < 16; ++j) {
            int q4 = ah + 2 * j;
            float4 v = *(const float4*)(xrow + q4 * 4);
            int k = q4 * 4;
            As[k+0][arow] = v.x; As[k+1][arow] = v.y; As[k+2][arow] = v.z; As[k+3][arow] = v.w;
        }
    }

    float bestv[8];
    int   besti[8];
    #pragma unroll
    for (int i = 0; i < 8; ++i) { bestv[i] = -3.4e38f; besti[i] = 0; }

    const int m0 = 4 * tr;           // first m-quad; second is 64+4*tr
    const int cbase = 4 * tc;        // c offsets: cbase + 64v + jj

    for (int c0 = 0; c0 < Cn; c0 += 256) {
        float acc[8][16];
        #pragma unroll
        for (int i = 0; i < 8; ++i)
            #pragma unroll
            for (int j = 0; j < 16; ++j) acc[i][j] = 0.f;

        for (int k0 = 0; k0 < DGn; k0 += 16) {
            __syncthreads();   // previous Es consumers done (also covers initial As staging)
            // stage E k-slice: thread t owns code c0+t, all 16 k. Writes 2-way (free).
            {
                const float* erow = eg + (size_t)(c0 + t) * DGn + k0;
                float4 e0 = *(const float4*)(erow);
                float4 e1 = *(const float4*)(erow + 4);
                float4 e2 = *(const float4*)(erow + 8);
                float4 e3 = *(const float4*)(erow + 12);
                Es[ 0][t] = e0.x; Es[ 1][t] = e0.y; Es[ 2][t] = e0.z; Es[ 3][t] = e0.w;
                Es[ 4][t] = e1.x; Es[ 5][t] = e1.y; Es[ 6][t] = e1.z; Es[ 7][t] = e1.w;
                Es[ 8][t] = e2.x; Es[ 9][t] = e2.y; Es[10][t] = e2.z; Es[11][t] = e2.w;
                Es[12][t] = e3.x; Es[13][t] = e3.y; Es[14][t] = e3.z; Es[15][t] = e3.w;
            }
            __syncthreads();
            #pragma unroll
            for (int kk = 0; kk < 16; ++kk) {
                float4 a0 = *(const float4*)&As[k0+kk][m0];
                float4 a1 = *(const float4*)&As[k0+kk][64 + m0];
                float4 b0 = *(const float4*)&Es[kk][cbase];
                float4 b1 = *(const float4*)&Es[kk][64 + cbase];
                float4 b2 = *(const float4*)&Es[kk][128 + cbase];
                float4 b3 = *(const float4*)&Es[kk][192 + cbase];
                float av[8] = {a0.x,a0.y,a0.z,a0.w,a1.x,a1.y,a1.z,a1.w};
                float bv[16] = {b0.x,b0.y,b0.z,b0.w,b1.x,b1.y,b1.z,b1.w,
                                b2.x,b2.y,b2.z,b2.w,b3.x,b3.y,b3.z,b3.w};
                #pragma unroll
                for (int i = 0; i < 8; ++i)
                    #pragma unroll
                    for (int j = 0; j < 16; ++j)
                        acc[i][j] = fmaf(av[i], bv[j], acc[i][j]);
            }
        }
        // running argmax: score = 2*f.E - ||E||^2  (||f||^2 constant per row, dropped)
        // in-thread scan is ascending c (v outer, jj inner); ties resolved in final reduce
        #pragma unroll
        for (int v = 0; v < 4; ++v) {
            float en[4];
            #pragma unroll
            for (int jj = 0; jj < 4; ++jj) en[jj] = enorm_g[c0 + 64*v + cbase + jj];
            #pragma unroll
            for (int i = 0; i < 8; ++i) {
                #pragma unroll
                for (int jj = 0; jj < 4; ++jj) {
                    int c = c0 + 64*v + cbase + jj;
                    float di = fmaf(2.0f, acc[i][4*v + jj], -en[jj]);
                    if (di > bestv[i]) { bestv[i] = di; besti[i] = c; }
                }
            }
        }
    }

    // ---- cross-thread argmax reduce (alias dead As/Es) ----
    float* redv = &As[0][0];                 // 128*16 floats
    int*   redi = ((int*)&As[0][0]) + 2048;  // 128*16 ints
    int*   idxf = (int*)&Es[0][0];           // 128 ints
    __syncthreads();
    #pragma unroll
    for (int i = 0; i < 8; ++i) {
        int m = (i < 4) ? (m0 + i) : (64 + m0 + i - 4);
        redv[m*16 + tc] = bestv[i];
        redi[m*16 + tc] = besti[i];
    }
    __syncthreads();
    if (t < 128) {
        float bv = redv[t*16]; int bi = redi[t*16];
        #pragma unroll
        for (int u = 1; u < 16; ++u) {
            float v2 = redv[t*16 + u]; int i2 = redi[t*16 + u];
            if (v2 > bv || (v2 == bv && i2 < bi)) { bv = v2; bi = i2; }
        }
        idxf[t] = bi;
        out[OFF_IND + (size_t)(n0 + t) * Gn + g] = (float)bi;
        atomicAdd(&out[OFF_CS + g*Cn + bi], 0.2f);
    }
    __syncthreads();

    // ---- quantize_st + embed_sum scatter + commit loss ----
    float lloss = 0.f;
    for (int j = 0; j < 64; ++j) {
        int e = j * 256 + t;
        int row = e >> 7, d = e & 127;
        int ci = idxf[row];
        float xv = xg[(size_t)row * Dn + d];
        float q  = eg[(size_t)ci * DGn + d];
        out[OFF_Q + (size_t)(n0+row) * Dn + g*DGn + d] = xv + (q - xv);
        atomicAdd(&out[OFF_AVG + ((size_t)g*Cn + ci)*DGn + d], 0.2f * xv);
        float df = q - xv;
        lloss += df * df;
    }
    #pragma unroll
    for (int off = 32; off; off >>= 1) lloss += __shfl_xor(lloss, off, 64);
    if ((t & 63) == 0) atomicAdd(&out[OFF_LOSS], lloss);
}

// per-g: total, laplace smoothing, new_embed = avg/smoothed; scale loss
__global__ void vq_finalize(float* __restrict__ out) {
    const int g = blockIdx.x >> 5;
    const int slice = blockIdx.x & 31;
    const int t = threadIdx.x;
    __shared__ float red[256];
    const float* ncs = out + OFF_CS + g * Cn;
    float s = 0.f;
    for (int c = t; c < Cn; c += 256) s += ncs[c];
    red[t] = s;
    __syncthreads();
    for (int w = 128; w; w >>= 1) {
        if (t < w) red[t] += red[t + w];
        __syncthreads();
    }
    float total = red[0];
    float denom = total + Cn * 1e-5f;
    const float* avg = out + OFF_AVG + (size_t)g * Cn * DGn;
    float* embo = out + OFF_EMB + (size_t)g * Cn * DGn;
    for (int u = 0; u < 32; ++u) {
        int e = slice * 8192 + u * 256 + t;
        int c = e >> 7;
        float sm = (ncs[c] + 1e-5f) / denom * total;
        embo[e] = avg[e] / sm;
    }
    if (blockIdx.x == 0 && t == 0) out[OFF_LOSS] *= (1.0f / 8388608.0f);
}

extern "C" void kernel_launch(void* const* d_in, const int* in_sizes, int n_in,
                              void* d_out, int out_size, void* d_ws, size_t ws_size,
                              hipStream_t stream) {
    const float* x    = (const float*)d_in[0];
    const float* emb  = (const float*)d_in[1];
    const float* cs   = (const float*)d_in[2];
    const float* eavg = (const float*)d_in[3];
    float* out = (float*)d_out;

    hipLaunchKernelGGL(vq_init,     dim3(4096), dim3(256), 0, stream, cs, eavg, out);
    hipLaunchKernelGGL(vq_enorm,    dim3(2048), dim3(256), 0, stream, emb, out);
    hipLaunchKernelGGL(vq_main,     dim3(512),  dim3(256), 0, stream, x, emb, out);
    hipLaunchKernelGGL(vq_finalize, dim3(128),  dim3(256), 0, stream, out);
}

// Round 3
// 1126.783 us; speedup vs baseline: 1.0101x; 1.0101x over previous
//
#include <hip/hip_runtime.h>

// Problem dims (fixed by the reference setup)
#define Bn 8
#define Sn 2048
#define Dn 512
#define Gn 4
#define Cn 2048
#define DGn 128
#define Nn 16384  // B*S

// d_out layout (flat fp32, reference return order)
#define OFF_Q    0u        // quantize_st  [8,2048,512]  = 8388608
#define OFF_IND  8388608u  // ind_out      [8,2048,4]    = 65536 (float-encoded ints)
#define OFF_LOSS 8454144u  // commit_loss  scalar
#define OFF_CS   8454145u  // new_cluster_size [4,2048]  = 8192
#define OFF_AVG  8462337u  // new_embed_avg [4,2048,128] = 1048576
#define OFF_EMB  9510913u  // new_embed     [4,2048,128] = 1048576 (first 8192 temporarily hold ||E||^2)

__global__ void vq_init(const float* __restrict__ cs_in,
                        const float* __restrict__ avg_in,
                        float* __restrict__ out) {
    int i = blockIdx.x * 256 + threadIdx.x;
    if (i < Gn * Cn * DGn) out[OFF_AVG + i] = 0.8f * avg_in[i];
    if (i < Gn * Cn)       out[OFF_CS + i]  = 0.8f * cs_in[i];
    if (i == 0)            out[OFF_LOSS] = 0.0f;
}

// one wave per code row: ||E[g,c]||^2 -> stash at OFF_EMB (overwritten by finalize)
__global__ void vq_enorm(const float* __restrict__ embed,
                         float* __restrict__ out) {
    int gid  = blockIdx.x * 256 + threadIdx.x;
    int wave = gid >> 6;            // 0..8191
    int lane = gid & 63;
    const float* row = embed + (size_t)wave * DGn;
    float a = row[lane], b = row[lane + 64];
    float v = fmaf(a, a, b * b);
    #pragma unroll
    for (int off = 32; off; off >>= 1) v += __shfl_xor(v, off, 64);
    if (lane == 0) out[OFF_EMB + wave] = v;
}

// Main fused kernel: block = (g, 128-row tile); c scanned in 256-wide tiles.
// 256 threads, per-thread 8m x 16c accumulators (128 acc VGPRs, ALL statically
// indexed — every loop touching register arrays is #pragma unroll'd; the R2
// version left the argmax v-loop un-unrolled -> acc went to scratch -> 1.5 GB
// of spill traffic). amdgpu_waves_per_eu(2,2) lets the allocator use up to
// 256 VGPRs (2 waves/EU = 8 waves/CU = 2 blocks/CU, matching 80 KB LDS).
__global__ __attribute__((amdgpu_flat_work_group_size(256, 256), amdgpu_waves_per_eu(2, 2)))
void vq_main(const float* __restrict__ x,
             const float* __restrict__ embed,
             float* __restrict__ out) {
    __shared__ float As[DGn][128];   // A transposed [k][m], 64 KB. bank = m%32 -> 2-way (free)
    __shared__ float Es[16][256];    // E k-slice [k][c], 16 KB.  bank = c%32 -> 2-way (free)

    const int t  = threadIdx.x;
    const int g  = blockIdx.x >> 7;
    const int n0 = (blockIdx.x & 127) * 128;
    const int tr = t & 15;           // m-lane
    const int tc = t >> 4;           // c-lane

    const float* xg = x + (size_t)n0 * Dn + g * DGn;
    const float* eg = embed + (size_t)g * Cn * DGn;
    const float* enorm_g = out + OFF_EMB + g * Cn;

    // ---- stage A transposed: lane-per-row mapping -> scalar writes 2-way (free) ----
    {
        const int arow = t & 127, ah = t >> 7;
        const float* xrow = xg + (size_t)arow * Dn;
        #pragma unroll
        for (int j = 0; j < 16; ++j) {
            int q4 = ah + 2 * j;
            float4 v = *(const float4*)(xrow + q4 * 4);
            int k = q4 * 4;
            As[k+0][arow] = v.x; As[k+1][arow] = v.y; As[k+2][arow] = v.z; As[k+3][arow] = v.w;
        }
    }

    float bestv[8];
    int   besti[8];
    #pragma unroll
    for (int i = 0; i < 8; ++i) { bestv[i] = -3.4e38f; besti[i] = 0; }

    const int m0 = 4 * tr;           // m-quads: m0 and 64+m0
    const int cbase = 4 * tc;        // c offsets: cbase + 64*v + jj

    for (int c0 = 0; c0 < Cn; c0 += 256) {
        float acc[8][16];
        #pragma unroll
        for (int i = 0; i < 8; ++i)
            #pragma unroll
            for (int j = 0; j < 16; ++j) acc[i][j] = 0.f;

        for (int k0 = 0; k0 < DGn; k0 += 16) {
            __syncthreads();   // previous consumers of Es done (also covers initial As staging)
            // stage E k-slice: thread t owns code c0+t, 16 k values. Writes 2-way (free).
            {
                const float* erow = eg + (size_t)(c0 + t) * DGn + k0;
                float4 e0 = *(const float4*)(erow);
                float4 e1 = *(const float4*)(erow + 4);
                float4 e2 = *(const float4*)(erow + 8);
                float4 e3 = *(const float4*)(erow + 12);
                Es[ 0][t] = e0.x; Es[ 1][t] = e0.y; Es[ 2][t] = e0.z; Es[ 3][t] = e0.w;
                Es[ 4][t] = e1.x; Es[ 5][t] = e1.y; Es[ 6][t] = e1.z; Es[ 7][t] = e1.w;
                Es[ 8][t] = e2.x; Es[ 9][t] = e2.y; Es[10][t] = e2.z; Es[11][t] = e2.w;
                Es[12][t] = e3.x; Es[13][t] = e3.y; Es[14][t] = e3.z; Es[15][t] = e3.w;
            }
            __syncthreads();
            #pragma unroll
            for (int kk = 0; kk < 16; ++kk) {
                float4 a0 = *(const float4*)&As[k0+kk][m0];
                float4 a1 = *(const float4*)&As[k0+kk][64 + m0];
                float4 b0 = *(const float4*)&Es[kk][cbase];
                float4 b1 = *(const float4*)&Es[kk][64 + cbase];
                float4 b2 = *(const float4*)&Es[kk][128 + cbase];
                float4 b3 = *(const float4*)&Es[kk][192 + cbase];
                float av[8] = {a0.x,a0.y,a0.z,a0.w,a1.x,a1.y,a1.z,a1.w};
                float bv[16] = {b0.x,b0.y,b0.z,b0.w,b1.x,b1.y,b1.z,b1.w,
                                b2.x,b2.y,b2.z,b2.w,b3.x,b3.y,b3.z,b3.w};
                #pragma unroll
                for (int i = 0; i < 8; ++i) {
                    float a = av[i];
                    #pragma unroll
                    for (int j = 0; j < 16; ++j)
                        acc[i][j] = fmaf(a, bv[j], acc[i][j]);
                }
            }
        }
        // running argmax: score = 2*f.E - ||E||^2 (||f||^2 constant per row, dropped).
        // FULLY unrolled: every acc index compile-time (rule #20 — runtime index -> scratch).
        #pragma unroll
        for (int v = 0; v < 4; ++v) {
            float en[4];
            #pragma unroll
            for (int jj = 0; jj < 4; ++jj) en[jj] = enorm_g[c0 + 64*v + cbase + jj];
            #pragma unroll
            for (int i = 0; i < 8; ++i) {
                #pragma unroll
                for (int jj = 0; jj < 4; ++jj) {
                    int c = c0 + 64*v + cbase + jj;
                    float di = fmaf(2.0f, acc[i][4*v + jj], -en[jj]);
                    if (di > bestv[i]) { bestv[i] = di; besti[i] = c; }
                }
            }
        }
    }

    // ---- cross-thread argmax reduce (alias dead As/Es) ----
    float* redv = &As[0][0];                 // 128*16 floats
    int*   redi = ((int*)&As[0][0]) + 2048;  // 128*16 ints
    int*   idxf = (int*)&Es[0][0];           // 128 ints
    __syncthreads();
    #pragma unroll
    for (int i = 0; i < 8; ++i) {
        int m = (i < 4) ? (m0 + i) : (64 + m0 + i - 4);
        redv[m*16 + tc] = bestv[i];
        redi[m*16 + tc] = besti[i];
    }
    __syncthreads();
    if (t < 128) {
        float bv = redv[t*16]; int bi = redi[t*16];
        #pragma unroll
        for (int u = 1; u < 16; ++u) {
            float v2 = redv[t*16 + u]; int i2 = redi[t*16 + u];
            if (v2 > bv || (v2 == bv && i2 < bi)) { bv = v2; bi = i2; }
        }
        idxf[t] = bi;
        out[OFF_IND + (size_t)(n0 + t) * Gn + g] = (float)bi;
        atomicAdd(&out[OFF_CS + g*Cn + bi], 0.2f);
    }
    __syncthreads();

    // ---- quantize_st + embed_sum scatter + commit loss ----
    float lloss = 0.f;
    for (int j = 0; j < 64; ++j) {
        int e = j * 256 + t;
        int row = e >> 7, d = e & 127;
        int ci = idxf[row];
        float xv = xg[(size_t)row * Dn + d];
        float q  = eg[(size_t)ci * DGn + d];
        out[OFF_Q + (size_t)(n0+row) * Dn + g*DGn + d] = xv + (q - xv);
        atomicAdd(&out[OFF_AVG + ((size_t)g*Cn + ci)*DGn + d], 0.2f * xv);
        float df = q - xv;
        lloss += df * df;
    }
    #pragma unroll
    for (int off = 32; off; off >>= 1) lloss += __shfl_xor(lloss, off, 64);
    if ((t & 63) == 0) atomicAdd(&out[OFF_LOSS], lloss);
}

// per-g: total, laplace smoothing, new_embed = avg/smoothed; scale loss
__global__ void vq_finalize(float* __restrict__ out) {
    const int g = blockIdx.x >> 5;
    const int slice = blockIdx.x & 31;
    const int t = threadIdx.x;
    __shared__ float red[256];
    const float* ncs = out + OFF_CS + g * Cn;
    float s = 0.f;
    for (int c = t; c < Cn; c += 256) s += ncs[c];
    red[t] = s;
    __syncthreads();
    for (int w = 128; w; w >>= 1) {
        if (t < w) red[t] += red[t + w];
        __syncthreads();
    }
    float total = red[0];
    float denom = total + Cn * 1e-5f;
    const float* avg = out + OFF_AVG + (size_t)g * Cn * DGn;
    float* embo = out + OFF_EMB + (size_t)g * Cn * DGn;
    for (int u = 0; u < 32; ++u) {
        int e = slice * 8192 + u * 256 + t;
        int c = e >> 7;
        float sm = (ncs[c] + 1e-5f) / denom * total;
        embo[e] = avg[e] / sm;
    }
    if (blockIdx.x == 0 && t == 0) out[OFF_LOSS] *= (1.0f / 8388608.0f);
}

extern "C" void kernel_launch(void* const* d_in, const int* in_sizes, int n_in,
                              void* d_out, int out_size, void* d_ws, size_t ws_size,
                              hipStream_t stream) {
    const float* x    = (const float*)d_in[0];
    const float* emb  = (const float*)d_in[1];
    const float* cs   = (const float*)d_in[2];
    const float* eavg = (const float*)d_in[3];
    float* out = (float*)d_out;

    hipLaunchKernelGGL(vq_init,     dim3(4096), dim3(256), 0, stream, cs, eavg, out);
    hipLaunchKernelGGL(vq_enorm,    dim3(2048), dim3(256), 0, stream, emb, out);
    hipLaunchKernelGGL(vq_main,     dim3(512),  dim3(256), 0, stream, x, emb, out);
    hipLaunchKernelGGL(vq_finalize, dim3(128),  dim3(256), 0, stream, out);
}

// Round 4
// 490.558 us; speedup vs baseline: 2.3201x; 2.2969x over previous
//
#include <hip/hip_runtime.h>

// Problem dims (fixed by the reference setup)
#define Bn 8
#define Sn 2048
#define Dn 512
#define Gn 4
#define Cn 2048
#define DGn 128
#define Nn 16384  // B*S

// d_out layout (flat fp32, reference return order)
#define OFF_Q    0u        // quantize_st  [8,2048,512]  = 8388608
#define OFF_IND  8388608u  // ind_out      [8,2048,4]    = 65536 (float-encoded ints)
#define OFF_LOSS 8454144u  // commit_loss  scalar
#define OFF_CS   8454145u  // new_cluster_size [4,2048]  = 8192
#define OFF_AVG  8462337u  // new_embed_avg [4,2048,128] = 1048576
#define OFF_EMB  9510913u  // new_embed     [4,2048,128] = 1048576 (first 8192 temporarily hold ||E||^2)

__global__ void vq_init(const float* __restrict__ cs_in,
                        const float* __restrict__ avg_in,
                        float* __restrict__ out) {
    int i = blockIdx.x * 256 + threadIdx.x;
    if (i < Gn * Cn * DGn) out[OFF_AVG + i] = 0.8f * avg_in[i];
    if (i < Gn * Cn)       out[OFF_CS + i]  = 0.8f * cs_in[i];
    if (i == 0)            out[OFF_LOSS] = 0.0f;
}

// one wave per code row: ||E[g,c]||^2 -> stash at OFF_EMB (overwritten by finalize)
__global__ void vq_enorm(const float* __restrict__ embed,
                         float* __restrict__ out) {
    int gid  = blockIdx.x * 256 + threadIdx.x;
    int wave = gid >> 6;            // 0..8191
    int lane = gid & 63;
    const float* row = embed + (size_t)wave * DGn;
    float a = row[lane], b = row[lane + 64];
    float v = fmaf(a, a, b * b);
    #pragma unroll
    for (int off = 32; off; off >>= 1) v += __shfl_xor(v, off, 64);
    if (lane == 0) out[OFF_EMB + wave] = v;
}

// Main fused kernel: block = (g, 128-row tile); c scanned in 128-wide tiles.
// 256 threads as 16x16; per-thread 8m x 8c accumulators (64 acc VGPRs — fits
// the 128-VGPR allocation with zero spill; the 8x16 variant spilled 1.3 GB).
// Fragments are two 4-wide quads (m0=4tr / 64+4tr, c0=4tc / 64+4tc) so every
// LDS access is <=2-way (free). LDS: 64K As + 8K Es = 72.5 KB -> 2 blocks/CU.
__launch_bounds__(256)
__global__ void vq_main(const float* __restrict__ x,
                        const float* __restrict__ embed,
                        float* __restrict__ out) {
    __shared__ float As[DGn][128];   // A transposed [k][m], 64 KB. bank = m%32 -> 2-way (free)
    __shared__ float Es[16][128];    // E k-slice [k][c], 8 KB.   bank = c%32 -> 2-way (free)
    __shared__ int   idxf[128];

    const int t  = threadIdx.x;
    const int g  = blockIdx.x >> 7;
    const int n0 = (blockIdx.x & 127) * 128;
    const int tr = t & 15;           // m-lane
    const int tc = t >> 4;           // c-lane

    const float* xg = x + (size_t)n0 * Dn + g * DGn;
    const float* eg = embed + (size_t)g * Cn * DGn;
    const float* enorm_g = out + OFF_EMB + g * Cn;

    // ---- stage A transposed: lane-per-row mapping -> scalar writes 2-way (free) ----
    {
        const int arow = t & 127, ah = t >> 7;
        const float* xrow = xg + (size_t)arow * Dn;
        #pragma unroll
        for (int j = 0; j < 16; ++j) {
            int q4 = ah + 2 * j;
            float4 v = *(const float4*)(xrow + q4 * 4);
            int k = q4 * 4;
            As[k+0][arow] = v.x; As[k+1][arow] = v.y; As[k+2][arow] = v.z; As[k+3][arow] = v.w;
        }
    }

    float bestv[8];
    int   besti[8];
    #pragma unroll
    for (int i = 0; i < 8; ++i) { bestv[i] = -3.4e38f; besti[i] = 0; }

    const int m0 = 4 * tr;           // m-quads: m0 and 64+m0
    const int cb = 4 * tc;           // c-quads: cb and 64+cb (within 128-wide tile)
    const int ec = t & 127;          // Es staging: code lane
    const int kh = (t >> 7) * 8;     // Es staging: k-half

    for (int c0 = 0; c0 < Cn; c0 += 128) {
        float acc[8][8];
        #pragma unroll
        for (int i = 0; i < 8; ++i)
            #pragma unroll
            for (int j = 0; j < 8; ++j) acc[i][j] = 0.f;

        for (int k0 = 0; k0 < DGn; k0 += 16) {
            __syncthreads();   // previous consumers of Es done (also covers initial As staging)
            // stage E k-slice [16][128]: thread owns (code ec, k-half kh): 8 floats.
            {
                const float* erow = eg + (size_t)(c0 + ec) * DGn + k0 + kh;
                float4 e0 = *(const float4*)(erow);
                float4 e1 = *(const float4*)(erow + 4);
                Es[kh+0][ec] = e0.x; Es[kh+1][ec] = e0.y; Es[kh+2][ec] = e0.z; Es[kh+3][ec] = e0.w;
                Es[kh+4][ec] = e1.x; Es[kh+5][ec] = e1.y; Es[kh+6][ec] = e1.z; Es[kh+7][ec] = e1.w;
            }
            __syncthreads();
            #pragma unroll
            for (int kk = 0; kk < 16; ++kk) {
                float4 a0 = *(const float4*)&As[k0+kk][m0];
                float4 a1 = *(const float4*)&As[k0+kk][64 + m0];
                float4 b0 = *(const float4*)&Es[kk][cb];
                float4 b1 = *(const float4*)&Es[kk][64 + cb];
                float av[8] = {a0.x,a0.y,a0.z,a0.w,a1.x,a1.y,a1.z,a1.w};
                float bv[8] = {b0.x,b0.y,b0.z,b0.w,b1.x,b1.y,b1.z,b1.w};
                #pragma unroll
                for (int i = 0; i < 8; ++i) {
                    float a = av[i];
                    #pragma unroll
                    for (int j = 0; j < 8; ++j)
                        acc[i][j] = fmaf(a, bv[j], acc[i][j]);
                }
            }
        }
        // running argmax: score = 2*f.E - ||E||^2 (||f||^2 constant per row, dropped).
        // Fully unrolled (rule #20: any runtime index on acc -> scratch).
        #pragma unroll
        for (int h = 0; h < 2; ++h) {
            #pragma unroll
            for (int jj = 0; jj < 4; ++jj) {
                int c = c0 + 64*h + cb + jj;
                float en = enorm_g[c];
                #pragma unroll
                for (int i = 0; i < 8; ++i) {
                    float di = fmaf(2.0f, acc[i][4*h + jj], -en);
                    if (di > bestv[i]) { bestv[i] = di; besti[i] = c; }
                }
            }
        }
    }

    // ---- cross-thread argmax reduce (alias dead As) ----
    float* redv = &As[0][0];                 // 128*16 floats
    int*   redi = ((int*)&As[0][0]) + 2048;  // 128*16 ints
    __syncthreads();
    #pragma unroll
    for (int i = 0; i < 8; ++i) {
        int m = (i < 4) ? (m0 + i) : (64 + m0 + i - 4);
        redv[m*16 + tc] = bestv[i];
        redi[m*16 + tc] = besti[i];
    }
    __syncthreads();
    if (t < 128) {
        float bv = redv[t*16]; int bi = redi[t*16];
        #pragma unroll
        for (int u = 1; u < 16; ++u) {
            float v2 = redv[t*16 + u]; int i2 = redi[t*16 + u];
            if (v2 > bv || (v2 == bv && i2 < bi)) { bv = v2; bi = i2; }
        }
        idxf[t] = bi;
        out[OFF_IND + (size_t)(n0 + t) * Gn + g] = (float)bi;
        atomicAdd(&out[OFF_CS + g*Cn + bi], 0.2f);
    }
    __syncthreads();

    // ---- quantize_st + embed_sum scatter + commit loss ----
    float lloss = 0.f;
    for (int j = 0; j < 64; ++j) {
        int e = j * 256 + t;
        int row = e >> 7, d = e & 127;
        int ci = idxf[row];
        float xv = xg[(size_t)row * Dn + d];
        float q  = eg[(size_t)ci * DGn + d];
        out[OFF_Q + (size_t)(n0+row) * Dn + g*DGn + d] = xv + (q - xv);
        atomicAdd(&out[OFF_AVG + ((size_t)g*Cn + ci)*DGn + d], 0.2f * xv);
        float df = q - xv;
        lloss += df * df;
    }
    #pragma unroll
    for (int off = 32; off; off >>= 1) lloss += __shfl_xor(lloss, off, 64);
    if ((t & 63) == 0) atomicAdd(&out[OFF_LOSS], lloss);
}

// per-g: total, laplace smoothing, new_embed = avg/smoothed; scale loss
__global__ void vq_finalize(float* __restrict__ out) {
    const int g = blockIdx.x >> 5;
    const int slice = blockIdx.x & 31;
    const int t = threadIdx.x;
    __shared__ float red[256];
    const float* ncs = out + OFF_CS + g * Cn;
    float s = 0.f;
    for (int c = t; c < Cn; c += 256) s += ncs[c];
    red[t] = s;
    __syncthreads();
    for (int w = 128; w; w >>= 1) {
        if (t < w) red[t] += red[t + w];
        __syncthreads();
    }
    float total = red[0];
    float denom = total + Cn * 1e-5f;
    const float* avg = out + OFF_AVG + (size_t)g * Cn * DGn;
    float* embo = out + OFF_EMB + (size_t)g * Cn * DGn;
    for (int u = 0; u < 32; ++u) {
        int e = slice * 8192 + u * 256 + t;
        int c = e >> 7;
        float sm = (ncs[c] + 1e-5f) / denom * total;
        embo[e] = avg[e] / sm;
    }
    if (blockIdx.x == 0 && t == 0) out[OFF_LOSS] *= (1.0f / 8388608.0f);
}

extern "C" void kernel_launch(void* const* d_in, const int* in_sizes, int n_in,
                              void* d_out, int out_size, void* d_ws, size_t ws_size,
                              hipStream_t stream) {
    const float* x    = (const float*)d_in[0];
    const float* emb  = (const float*)d_in[1];
    const float* cs   = (const float*)d_in[2];
    const float* eavg = (const float*)d_in[3];
    float* out = (float*)d_out;

    hipLaunchKernelGGL(vq_init,     dim3(4096), dim3(256), 0, stream, cs, eavg, out);
    hipLaunchKernelGGL(vq_enorm,    dim3(2048), dim3(256), 0, stream, emb, out);
    hipLaunchKernelGGL(vq_main,     dim3(512),  dim3(256), 0, stream, x, emb, out);
    hipLaunchKernelGGL(vq_finalize, dim3(128),  dim3(256), 0, stream, out);
}